// Round 1
// baseline (159.534 us; speedup 1.0000x reference)
//
#include <hip/hip_runtime.h>

#define N_TRI   256
#define TSTRIDE 36   // floats per triangle row; 144 B = 9x16 B -> rows 16B-aligned

__global__ __launch_bounds__(256) void tri_sdf_kernel(
    const float* __restrict__ p, const float* __restrict__ points,
    float* __restrict__ out, int n_pts)
{
    __shared__ float tri[N_TRI * TSTRIDE];   // 36 KB

    const int tid = threadIdx.x;

    // ---- per-block triangle precompute: thread t -> triangle t ----
    {
        const float* tp = points + tid * 9;
        float Ax = tp[0], Ay = tp[1], Az = tp[2];
        float Bx = tp[3], By = tp[4], Bz = tp[5];
        float Cx = tp[6], Cy = tp[7], Cz = tp[8];

        float acx = Ax - Cx, acy = Ay - Cy, acz = Az - Cz;
        float bax = Bx - Ax, bay = By - Ay, baz = Bz - Az;
        float cbx = Cx - Bx, cby = Cy - By, cbz = Cz - Bz;

        // nor = cross(ba, ac)
        float nx = bay * acz - baz * acy;
        float ny = baz * acx - bax * acz;
        float nz = bax * acy - bay * acx;

        // cross(ba, nor), cross(cb, nor), cross(ac, nor)
        float c1x = bay * nz - baz * ny, c1y = baz * nx - bax * nz, c1z = bax * ny - bay * nx;
        float c2x = cby * nz - cbz * ny, c2y = cbz * nx - cbx * nz, c2z = cbx * ny - cby * nx;
        float c3x = acy * nz - acz * ny, c3y = acz * nx - acx * nz, c3z = acx * ny - acy * nx;

        float* s = tri + tid * TSTRIDE;
        s[0]  = Ax;  s[1]  = Ay;  s[2]  = Az;
        s[3]  = Bx;  s[4]  = By;  s[5]  = Bz;
        s[6]  = Cx;  s[7]  = Cy;  s[8]  = Cz;
        s[9]  = bax; s[10] = bay; s[11] = baz;
        s[12] = cbx; s[13] = cby; s[14] = cbz;
        s[15] = acx; s[16] = acy; s[17] = acz;
        s[18] = nx;  s[19] = ny;  s[20] = nz;
        s[21] = c1x; s[22] = c1y; s[23] = c1z;
        s[24] = c2x; s[25] = c2y; s[26] = c2z;
        s[27] = c3x; s[28] = c3y; s[29] = c3z;
        s[30] = 1.0f / (bax * bax + bay * bay + baz * baz);
        s[31] = 1.0f / (cbx * cbx + cby * cby + cbz * cbz);
        s[32] = 1.0f / (acx * acx + acy * acy + acz * acz);
        s[33] = 1.0f / (nx * nx + ny * ny + nz * nz);
        s[34] = 0.0f; s[35] = 0.0f;
    }
    __syncthreads();

    const int i = blockIdx.x * blockDim.x + tid;
    if (i >= n_pts) return;

    const float px = p[3 * i + 0];
    const float py = p[3 * i + 1];
    const float pz = p[3 * i + 2];

    float sum = 0.0f;

    // exp(-32*(d-0.04)) = exp2( d * (-32*log2e) + (32*0.04*log2e) )
    const float EK = -46.166241308446834f;   // -32 * log2(e)
    const float EB = 1.8466496523378732f;    //  32 * 0.04 * log2(e)

#pragma unroll 2
    for (int j = 0; j < N_TRI; ++j) {
        const float* s = tri + j * TSTRIDE;

        float Ax = s[0],  Ay = s[1],  Az = s[2];
        float Bx = s[3],  By = s[4],  Bz = s[5];
        float Cx = s[6],  Cy = s[7],  Cz = s[8];
        float bax = s[9],  bay = s[10], baz = s[11];
        float cbx = s[12], cby = s[13], cbz = s[14];
        float acx = s[15], acy = s[16], acz = s[17];
        float nx = s[18],  ny = s[19],  nz = s[20];
        float c1x = s[21], c1y = s[22], c1z = s[23];
        float c2x = s[24], c2y = s[25], c2z = s[26];
        float c3x = s[27], c3y = s[28], c3z = s[29];
        float inv_ba = s[30], inv_cb = s[31], inv_ac = s[32], inv_nor = s[33];

        float pax = px - Ax, pay = py - Ay, paz = pz - Az;
        float pbx = px - Bx, pby = py - By, pbz = pz - Bz;
        float pcx = px - Cx, pcy = py - Cy, pcz = pz - Cz;

        // sidedness: sign(dot(cross(ba,nor),pa)) + sign(dot(cross(cb,nor),pb)) + sign(dot(cross(ac,nor),pc))
        float s1 = c1x * pax + c1y * pay + c1z * paz;
        float s2 = c2x * pbx + c2y * pby + c2z * pbz;
        float s3 = c3x * pcx + c3y * pcy + c3z * pcz;
        float sgn = ((s1 > 0.0f ? 1.0f : 0.0f) - (s1 < 0.0f ? 1.0f : 0.0f))
                  + ((s2 > 0.0f ? 1.0f : 0.0f) - (s2 < 0.0f ? 1.0f : 0.0f))
                  + ((s3 > 0.0f ? 1.0f : 0.0f) - (s3 < 0.0f ? 1.0f : 0.0f));

        // segment distances (direct form for accuracy)
        float t1 = fminf(fmaxf((bax * pax + bay * pay + baz * paz) * inv_ba, 0.0f), 1.0f);
        float d1x = bax * t1 - pax, d1y = bay * t1 - pay, d1z = baz * t1 - paz;
        float e1 = d1x * d1x + d1y * d1y + d1z * d1z;

        float t2 = fminf(fmaxf((cbx * pbx + cby * pby + cbz * pbz) * inv_cb, 0.0f), 1.0f);
        float d2x = cbx * t2 - pbx, d2y = cby * t2 - pby, d2z = cbz * t2 - pbz;
        float e2 = d2x * d2x + d2y * d2y + d2z * d2z;

        float t3 = fminf(fmaxf((acx * pcx + acy * pcy + acz * pcz) * inv_ac, 0.0f), 1.0f);
        float d3x = acx * t3 - pcx, d3y = acy * t3 - pcy, d3z = acz * t3 - pcz;
        float e3 = d3x * d3x + d3y * d3y + d3z * d3z;

        float same = fminf(fminf(e1, e2), e3);

        float dn = nx * pax + ny * pay + nz * paz;
        float opp = dn * dn * inv_nor;

        float d2v = (sgn < 2.0f) ? same : opp;
        float d = sqrtf(fmaxf(d2v, 1e-8f));

        sum += exp2f(fmaf(d, EK, EB));
    }

    // -log(max(sum,1e-6))/32 = -log2(max(sum,1e-6)) * ln2/32
    out[i] = -log2f(fmaxf(sum, 1e-6f)) * 0.02166084939249829f;
}

extern "C" void kernel_launch(void* const* d_in, const int* in_sizes, int n_in,
                              void* d_out, int out_size, void* d_ws, size_t ws_size,
                              hipStream_t stream) {
    const float* p      = (const float*)d_in[0];
    const float* points = (const float*)d_in[1];
    float* out          = (float*)d_out;
    const int n_pts = in_sizes[0] / 3;
    const int blocks = (n_pts + 255) / 256;
    hipLaunchKernelGGL(tri_sdf_kernel, dim3(blocks), dim3(256), 0, stream,
                       p, points, out, n_pts);
}

// Round 2
// 128.389 us; speedup vs baseline: 1.2426x; 1.2426x over previous
//
#include <hip/hip_runtime.h>

#define N_TRI   256
#define PSTRIDE 32   // floats per precomputed triangle row; 128 B -> s_load_dwordx16 x2
#define N_PTS   131072

// ---------------- Kernel A: per-triangle invariants -> d_ws -----------------
__global__ __launch_bounds__(256) void tri_pre_kernel(
    const float* __restrict__ points, float* __restrict__ pre)
{
    const int t = threadIdx.x;   // one triangle per thread, 1 block of 256
    const float* tp = points + t * 9;
    float Ax = tp[0], Ay = tp[1], Az = tp[2];
    float Bx = tp[3], By = tp[4], Bz = tp[5];
    float Cx = tp[6], Cy = tp[7], Cz = tp[8];

    float acx = Ax - Cx, acy = Ay - Cy, acz = Az - Cz;
    float bax = Bx - Ax, bay = By - Ay, baz = Bz - Az;
    float cbx = Cx - Bx, cby = Cy - By, cbz = Cz - Bz;

    // nor = cross(ba, ac)
    float nx = bay * acz - baz * acy;
    float ny = baz * acx - bax * acz;
    float nz = bax * acy - bay * acx;

    // cross(ba, nor), cross(cb, nor), cross(ac, nor)
    float c1x = bay * nz - baz * ny, c1y = baz * nx - bax * nz, c1z = bax * ny - bay * nx;
    float c2x = cby * nz - cbz * ny, c2y = cbz * nx - cbx * nz, c2z = cbx * ny - cby * nx;
    float c3x = acy * nz - acz * ny, c3y = acz * nx - acx * nz, c3z = acx * ny - acy * nx;

    float* s = pre + t * PSTRIDE;
    s[0]  = Ax;  s[1]  = Ay;  s[2]  = Az;
    s[3]  = bax; s[4]  = bay; s[5]  = baz;
    s[6]  = cbx; s[7]  = cby; s[8]  = cbz;
    s[9]  = acx; s[10] = acy; s[11] = acz;
    s[12] = nx;  s[13] = ny;  s[14] = nz;
    s[15] = c1x; s[16] = c1y; s[17] = c1z;
    s[18] = c2x; s[19] = c2y; s[20] = c2z;
    s[21] = c3x; s[22] = c3y; s[23] = c3z;
    s[24] = 1.0f / (bax * bax + bay * bay + baz * baz);
    s[25] = 1.0f / (cbx * cbx + cby * cby + cbz * cbz);
    s[26] = 1.0f / (acx * acx + acy * acy + acz * acz);
    s[27] = 1.0f / (nx * nx + ny * ny + nz * nz);
    s[28] = 0.0f; s[29] = 0.0f; s[30] = 0.0f; s[31] = 0.0f;
}

// ---------------- Kernel B: main loop, scalar-load triangle data ------------
// Block = 256 threads = 4 waves. Each block covers 64 points; wave w handles
// triangle chunk [w*64, w*64+64). Triangle data reads are wave-uniform ->
// s_load_dwordx16 through the scalar path, leaving VALU for the math.
__global__ __launch_bounds__(256) void tri_main_kernel(
    const float* __restrict__ p, const float* __restrict__ pre,
    float* __restrict__ out)
{
    __shared__ float red[4][64];

    const int tid  = threadIdx.x;
    const int lane = tid & 63;
    const int chunk = __builtin_amdgcn_readfirstlane(tid >> 6);  // wave-uniform

    const int pt = blockIdx.x * 64 + lane;
    const float px = p[3 * pt + 0];
    const float py = p[3 * pt + 1];
    const float pz = p[3 * pt + 2];

    float sum = 0.0f;

    // exp(-32*(d-0.04)) = exp2(d * (-32*log2e) + 32*0.04*log2e)
    const float EK = -46.166241308446834f;
    const float EB = 1.8466496523378732f;

    const float* base = pre + chunk * (64 * PSTRIDE);

#pragma unroll 2
    for (int jj = 0; jj < 64; ++jj) {
        const float* s = base + jj * PSTRIDE;   // uniform address -> SMEM

        float Ax = s[0],  Ay = s[1],  Az = s[2];
        float bax = s[3],  bay = s[4],  baz = s[5];
        float cbx = s[6],  cby = s[7],  cbz = s[8];
        float acx = s[9],  acy = s[10], acz = s[11];
        float nx  = s[12], ny  = s[13], nz  = s[14];
        float c1x = s[15], c1y = s[16], c1z = s[17];
        float c2x = s[18], c2y = s[19], c2z = s[20];
        float c3x = s[21], c3y = s[22], c3z = s[23];
        float inv_ba = s[24], inv_cb = s[25], inv_ac = s[26], inv_nor = s[27];

        float pax = px - Ax,  pay = py - Ay,  paz = pz - Az;
        float pbx = pax - bax, pby = pay - bay, pbz = paz - baz;   // p - B
        float pcx = pbx - cbx, pcy = pby - cby, pcz = pbz - cbz;   // p - C

        // sidedness >= 2  <=>  med3(s1,s2,s3) > 0  AND  min3(s1,s2,s3) >= 0
        float s1 = c1x * pax + c1y * pay + c1z * paz;
        float s2 = c2x * pbx + c2y * pby + c2z * pbz;
        float s3 = c3x * pcx + c3y * pcy + c3z * pcz;
        float mn  = fminf(fminf(s1, s2), s3);
        float med = __builtin_amdgcn_fmed3f(s1, s2, s3);
        bool inside = (med > 0.0f) & (mn >= 0.0f);

        // segment distances
        float t1 = __builtin_amdgcn_fmed3f((bax * pax + bay * pay + baz * paz) * inv_ba, 0.0f, 1.0f);
        float d1x = bax * t1 - pax, d1y = bay * t1 - pay, d1z = baz * t1 - paz;
        float e1 = d1x * d1x + d1y * d1y + d1z * d1z;

        float t2 = __builtin_amdgcn_fmed3f((cbx * pbx + cby * pby + cbz * pbz) * inv_cb, 0.0f, 1.0f);
        float d2x = cbx * t2 - pbx, d2y = cby * t2 - pby, d2z = cbz * t2 - pbz;
        float e2 = d2x * d2x + d2y * d2y + d2z * d2z;

        float t3 = __builtin_amdgcn_fmed3f((acx * pcx + acy * pcy + acz * pcz) * inv_ac, 0.0f, 1.0f);
        float d3x = acx * t3 - pcx, d3y = acy * t3 - pcy, d3z = acz * t3 - pcz;
        float e3 = d3x * d3x + d3y * d3y + d3z * d3z;

        float same = fminf(fminf(e1, e2), e3);

        float dn = nx * pax + ny * pay + nz * paz;
        float opp = dn * dn * inv_nor;

        float d2v = inside ? opp : same;
        float d = sqrtf(fmaxf(d2v, 1e-8f));

        sum += exp2f(fmaf(d, EK, EB));
    }

    red[chunk][lane] = sum;
    __syncthreads();

    if (tid < 64) {
        float total = ((red[0][tid] + red[1][tid]) + red[2][tid]) + red[3][tid];
        out[blockIdx.x * 64 + tid] =
            -log2f(fmaxf(total, 1e-6f)) * 0.02166084939249829f;
    }
}

extern "C" void kernel_launch(void* const* d_in, const int* in_sizes, int n_in,
                              void* d_out, int out_size, void* d_ws, size_t ws_size,
                              hipStream_t stream) {
    const float* p      = (const float*)d_in[0];
    const float* points = (const float*)d_in[1];
    float* out          = (float*)d_out;
    float* pre          = (float*)d_ws;          // 256 * 32 * 4 B = 32 KB

    hipLaunchKernelGGL(tri_pre_kernel, dim3(1), dim3(256), 0, stream, points, pre);

    const int n_pts = in_sizes[0] / 3;
    const int blocks = (n_pts + 63) / 64;        // 2048 for 131072 pts
    hipLaunchKernelGGL(tri_main_kernel, dim3(blocks), dim3(256), 0, stream,
                       p, pre, out);
}

// Round 3
// 99.817 us; speedup vs baseline: 1.5983x; 1.2862x over previous
//
#include <hip/hip_runtime.h>

typedef float f2 __attribute__((ext_vector_type(2)));

#define N_TRI   256
#define PSTRIDE 32   // floats per precomputed triangle row; 128 B

// ---------------- Kernel A: per-triangle invariants -> d_ws -----------------
__global__ __launch_bounds__(256) void tri_pre_kernel(
    const float* __restrict__ points, float* __restrict__ pre)
{
    const int t = threadIdx.x;   // one triangle per thread, 1 block of 256
    const float* tp = points + t * 9;
    float Ax = tp[0], Ay = tp[1], Az = tp[2];
    float Bx = tp[3], By = tp[4], Bz = tp[5];
    float Cx = tp[6], Cy = tp[7], Cz = tp[8];

    float acx = Ax - Cx, acy = Ay - Cy, acz = Az - Cz;
    float bax = Bx - Ax, bay = By - Ay, baz = Bz - Az;
    float cbx = Cx - Bx, cby = Cy - By, cbz = Cz - Bz;

    // nor = cross(ba, ac)
    float nx = bay * acz - baz * acy;
    float ny = baz * acx - bax * acz;
    float nz = bax * acy - bay * acx;

    // cross(ba, nor), cross(cb, nor), cross(ac, nor)
    float c1x = bay * nz - baz * ny, c1y = baz * nx - bax * nz, c1z = bax * ny - bay * nx;
    float c2x = cby * nz - cbz * ny, c2y = cbz * nx - cbx * nz, c2z = cbx * ny - cby * nx;
    float c3x = acy * nz - acz * ny, c3y = acz * nx - acx * nz, c3z = acx * ny - acy * nx;

    float* s = pre + t * PSTRIDE;
    s[0]  = Ax;  s[1]  = Ay;  s[2]  = Az;
    s[3]  = bax; s[4]  = bay; s[5]  = baz;
    s[6]  = cbx; s[7]  = cby; s[8]  = cbz;
    s[9]  = acx; s[10] = acy; s[11] = acz;
    s[12] = nx;  s[13] = ny;  s[14] = nz;
    s[15] = c1x; s[16] = c1y; s[17] = c1z;
    s[18] = c2x; s[19] = c2y; s[20] = c2z;
    s[21] = c3x; s[22] = c3y; s[23] = c3z;
    s[24] = 1.0f / (bax * bax + bay * bay + baz * baz);
    s[25] = 1.0f / (cbx * cbx + cby * cby + cbz * cbz);
    s[26] = 1.0f / (acx * acx + acy * acy + acz * acz);
    s[27] = 1.0f / (nx * nx + ny * ny + nz * nz);
    s[28] = 0.0f; s[29] = 0.0f; s[30] = 0.0f; s[31] = 0.0f;
}

// ---------------- Kernel B: main loop ---------------------------------------
// Block = 256 threads = 4 waves; block covers 128 points (2 per thread, packed
// fp32 math -> v_pk_fma_f32 etc). Wave w handles triangle chunk [w*64, w*64+64).
// Triangle data reads are wave-uniform -> s_load through the scalar path.
__global__ __launch_bounds__(256) void tri_main_kernel(
    const float* __restrict__ p, const float* __restrict__ pre,
    float* __restrict__ out)
{
    __shared__ float red[4][128];

    const int tid  = threadIdx.x;
    const int lane = tid & 63;
    const int chunk = __builtin_amdgcn_readfirstlane(tid >> 6);  // wave-uniform

    const int pt0 = blockIdx.x * 128 + lane;
    const int pt1 = pt0 + 64;

    f2 px = { p[3 * pt0 + 0], p[3 * pt1 + 0] };
    f2 py = { p[3 * pt0 + 1], p[3 * pt1 + 1] };
    f2 pz = { p[3 * pt0 + 2], p[3 * pt1 + 2] };

    f2 sum = {0.0f, 0.0f};

    // exp(-32*(d-0.04)) = exp2(d * (-32*log2e) + 32*0.04*log2e)
    const float EK = -46.166241308446834f;
    const float EB = 1.8466496523378732f;

    const float* base = pre + chunk * (64 * PSTRIDE);

#pragma unroll 2
    for (int jj = 0; jj < 64; ++jj) {
        const float* s = base + jj * PSTRIDE;   // uniform address -> SMEM

        float Ax = s[0],  Ay = s[1],  Az = s[2];
        float bax = s[3],  bay = s[4],  baz = s[5];
        float cbx = s[6],  cby = s[7],  cbz = s[8];
        float acx = s[9],  acy = s[10], acz = s[11];
        float nx  = s[12], ny  = s[13], nz  = s[14];
        float c1x = s[15], c1y = s[16], c1z = s[17];
        float c2x = s[18], c2y = s[19], c2z = s[20];
        float c3x = s[21], c3y = s[22], c3z = s[23];
        float inv_ba = s[24], inv_cb = s[25], inv_ac = s[26], inv_nor = s[27];

        f2 pax = px - Ax,  pay = py - Ay,  paz = pz - Az;
        f2 pbx = pax - bax, pby = pay - bay, pbz = paz - baz;   // p - B
        f2 pcx = pbx - cbx, pcy = pby - cby, pcz = pbz - cbz;   // p - C

        // sidedness signs
        f2 s1 = c1x * pax + c1y * pay + c1z * paz;
        f2 s2 = c2x * pbx + c2y * pby + c2z * pbz;
        f2 s3 = c3x * pcx + c3y * pcy + c3z * pcz;
        f2 mn = __builtin_elementwise_min(__builtin_elementwise_min(s1, s2), s3);

        // segment distances
        f2 t1 = (bax * pax + bay * pay + baz * paz) * inv_ba;
        f2 t2 = (cbx * pbx + cby * pby + cbz * pbz) * inv_cb;
        f2 t3 = (acx * pcx + acy * pcy + acz * pcz) * inv_ac;
        t1.x = __builtin_amdgcn_fmed3f(t1.x, 0.0f, 1.0f);
        t1.y = __builtin_amdgcn_fmed3f(t1.y, 0.0f, 1.0f);
        t2.x = __builtin_amdgcn_fmed3f(t2.x, 0.0f, 1.0f);
        t2.y = __builtin_amdgcn_fmed3f(t2.y, 0.0f, 1.0f);
        t3.x = __builtin_amdgcn_fmed3f(t3.x, 0.0f, 1.0f);
        t3.y = __builtin_amdgcn_fmed3f(t3.y, 0.0f, 1.0f);

        f2 d1x = bax * t1 - pax, d1y = bay * t1 - pay, d1z = baz * t1 - paz;
        f2 e1  = d1x * d1x + d1y * d1y + d1z * d1z;
        f2 d2x = cbx * t2 - pbx, d2y = cby * t2 - pby, d2z = cbz * t2 - pbz;
        f2 e2  = d2x * d2x + d2y * d2y + d2z * d2z;
        f2 d3x = acx * t3 - pcx, d3y = acy * t3 - pcy, d3z = acz * t3 - pcz;
        f2 e3  = d3x * d3x + d3y * d3y + d3z * d3z;

        f2 same = __builtin_elementwise_min(__builtin_elementwise_min(e1, e2), e3);

        f2 dn  = nx * pax + ny * pay + nz * paz;
        f2 opp = (dn * dn) * inv_nor;

        // inside <=> min3(s)>=0 AND med3(s)>0  (== sign-sum >= 2)
        float med0 = __builtin_amdgcn_fmed3f(s1.x, s2.x, s3.x);
        float med1 = __builtin_amdgcn_fmed3f(s1.y, s2.y, s3.y);
        bool in0 = (med0 > 0.0f) & (mn.x >= 0.0f);
        bool in1 = (med1 > 0.0f) & (mn.y >= 0.0f);
        float q0 = in0 ? opp.x : same.x;
        float q1 = in1 ? opp.y : same.y;

        float dd0 = __builtin_amdgcn_sqrtf(fmaxf(q0, 1e-8f));
        float dd1 = __builtin_amdgcn_sqrtf(fmaxf(q1, 1e-8f));

        f2 ea = (f2){dd0, dd1} * EK + EB;
        sum += (f2){ __builtin_amdgcn_exp2f(ea.x), __builtin_amdgcn_exp2f(ea.y) };
    }

    red[chunk][lane]      = sum.x;
    red[chunk][lane + 64] = sum.y;
    __syncthreads();

    if (tid < 128) {
        float total = ((red[0][tid] + red[1][tid]) + red[2][tid]) + red[3][tid];
        out[blockIdx.x * 128 + tid] =
            -__builtin_amdgcn_logf(fmaxf(total, 1e-6f)) * 0.02166084939249829f;
    }
}

extern "C" void kernel_launch(void* const* d_in, const int* in_sizes, int n_in,
                              void* d_out, int out_size, void* d_ws, size_t ws_size,
                              hipStream_t stream) {
    const float* p      = (const float*)d_in[0];
    const float* points = (const float*)d_in[1];
    float* out          = (float*)d_out;
    float* pre          = (float*)d_ws;          // 256 * 32 * 4 B = 32 KB

    hipLaunchKernelGGL(tri_pre_kernel, dim3(1), dim3(256), 0, stream, points, pre);

    const int n_pts = in_sizes[0] / 3;
    const int blocks = (n_pts + 127) / 128;      // 1024 for 131072 pts
    hipLaunchKernelGGL(tri_main_kernel, dim3(blocks), dim3(256), 0, stream,
                       p, pre, out);
}